// Round 7
// baseline (557.697 us; speedup 1.0000x reference)
//
#include <hip/hip_runtime.h>
#include <hip/hip_cooperative_groups.h>

// GCNConv forward: out = D^-1/2 (A+I) D^-1/2 (x W^T) + b
// N=100000, E=1600000, DIM=128. fp32 in/out, edge_index as int32.
//
// R12: prefix stuck at ~160us across ALL role slicings (R6/R8/R9/R11) while
// its traffic is ~25us worth => dispatch serialization/tails, not work, is the
// pole. Collapse to ONE cooperative kernel with grid.sync() phases:
//   A: scatter (blocks 0..SB-1) || MFMA gemm (blocks SB..G-1)   [independent]
//   B: per-bin LDS counting sort -> col/rowinfo/dinv (R9-verified)
//   C: register aggregate (R6-verified 66us structure), grid-stride
// Pre-dispatches: memset(cursors), wconv (tiny).

namespace cg = cooperative_groups;

#define DIM 128
#define BINSHIFT 8
#define BINSZ 256            // nodes per bin
#define NB 391               // ceil(100000/256)
#define CAPB 8192            // edges per bin capacity (mean 4096, sd ~64)
#define BUFCAP 32            // LDS slots per bin per scatter block
#define WSTRIDE 136          // shorts per LDS row in gemm epilogue buffer
#define SMEMSZ 51616         // max role: scatter cnt(1568 aligned) + sbuf(50048)

typedef __attribute__((ext_vector_type(8))) short short8;
typedef __attribute__((ext_vector_type(4))) float f32x4;
typedef __attribute__((ext_vector_type(4))) unsigned short ushort4v;

__device__ inline unsigned short f2bf(float f) {
    unsigned u = __builtin_bit_cast(unsigned, f);
    return (unsigned short)((u + 0x7FFFu + ((u >> 16) & 1u)) >> 16);
}
__device__ inline float bflo(unsigned u) { return __builtin_bit_cast(float, u << 16); }
__device__ inline float bfhi(unsigned u) { return __builtin_bit_cast(float, u & 0xFFFF0000u); }

__device__ inline void bf8_axpy(uint4 v, float s, float* acc) {
    acc[0] = fmaf(s, bflo(v.x), acc[0]);
    acc[1] = fmaf(s, bfhi(v.x), acc[1]);
    acc[2] = fmaf(s, bflo(v.y), acc[2]);
    acc[3] = fmaf(s, bfhi(v.y), acc[3]);
    acc[4] = fmaf(s, bflo(v.z), acc[4]);
    acc[5] = fmaf(s, bfhi(v.z), acc[5]);
    acc[6] = fmaf(s, bflo(v.w), acc[6]);
    acc[7] = fmaf(s, bfhi(v.w), acc[7]);
}

// ---- tiny pre-kernel: W -> bf16 --------------------------------------------
__global__ __launch_bounds__(256) void wconv(const float* __restrict__ W,
                                             unsigned short* __restrict__ wbf) {
    int base = blockIdx.x * 1024 + threadIdx.x * 4;
#pragma unroll
    for (int i = 0; i < 4; ++i) {
        float4 w4 = ((const float4*)W)[base + i];
        ushort4v o; o.x = f2bf(w4.x); o.y = f2bf(w4.y); o.z = f2bf(w4.z); o.w = f2bf(w4.w);
        ((ushort4v*)wbf)[base + i] = o;
    }
}

// ---- the mega kernel --------------------------------------------------------
__global__ __launch_bounds__(512, 6) void gcn_mega(
        const int* __restrict__ ei, int E,
        int* __restrict__ binCursor, unsigned* __restrict__ binned,
        int* __restrict__ col, int2* __restrict__ rowinfo, float* __restrict__ dinv,
        const float* __restrict__ x, const unsigned short* __restrict__ wbf,
        unsigned short* __restrict__ xlin,
        const float* __restrict__ bias, float* __restrict__ out,
        int N, int SB) {
    __shared__ __align__(16) char smem[SMEMSZ];
    cg::grid_group grid = cg::this_grid();
    int t = threadIdx.x;
    int bid = blockIdx.x;
    int G = gridDim.x;

    // ================= Phase A: scatter || gemm =================
    if (bid < SB) {
        // ---- scatter role (R10-verified bucket design)
        int* cnt = (int*)smem;
        unsigned* sbuf = (unsigned*)(smem + 1568);
        for (int i = t; i < NB; i += 512) cnt[i] = 0;
        __syncthreads();
        int chunk = (E + SB - 1) / SB;
        int base = bid * chunk, end = min(E, base + chunk);
        for (int i = base + t; i < end; i += 512) {
            int s = ei[i];
            int d = ei[E + i];
            int b = d >> BINSHIFT;
            unsigned p = ((unsigned)(d & (BINSZ - 1)) << 17) | (unsigned)s;
            int pos = atomicAdd(&cnt[b], 1);
            if (pos < BUFCAP) sbuf[b * BUFCAP + pos] = p;
            else binned[(size_t)b * CAPB + atomicAdd(&binCursor[b], 1)] = p;  // rare
        }
        __syncthreads();
        for (int b = t; b < NB; b += 512) {
            int c = min(cnt[b], BUFCAP);
            if (c > 0) {
                int gb = atomicAdd(&binCursor[b], c);
                unsigned* gp = binned + (size_t)b * CAPB + gb;
                const unsigned* lp = &sbuf[b * BUFCAP];
                for (int j = 0; j < c; ++j) gp[j] = lp[j];
            }
        }
    } else {
        // ---- gemm role: grid-stride over 128-row groups (R6-verified math)
        unsigned short* obuf = (unsigned short*)smem;
        int wid = t >> 6, lane = t & 63;
        int m = lane & 15, quad = lane >> 4;
        int GBn = (N + 127) >> 7;
        for (int grp = bid - SB; grp < GBn; grp += (G - SB)) {
            int row_base = grp * 128 + wid * 16;
            f32x4 acc[8];
#pragma unroll
            for (int j = 0; j < 8; ++j) acc[j] = (f32x4){0.f, 0.f, 0.f, 0.f};
            int arow = row_base + m;
            if (arow >= N) arow = N - 1;
            const float* xr = x + (size_t)arow * DIM + quad * 8;
#pragma unroll
            for (int kc = 0; kc < 4; ++kc) {
                float4 a0 = *(const float4*)(xr + kc * 32);
                float4 a1 = *(const float4*)(xr + kc * 32 + 4);
                short8 af;
                af[0] = (short)f2bf(a0.x); af[1] = (short)f2bf(a0.y);
                af[2] = (short)f2bf(a0.z); af[3] = (short)f2bf(a0.w);
                af[4] = (short)f2bf(a1.x); af[5] = (short)f2bf(a1.y);
                af[6] = (short)f2bf(a1.z); af[7] = (short)f2bf(a1.w);
#pragma unroll
                for (int jt = 0; jt < 8; ++jt) {
                    short8 bf = *(const short8*)&wbf[(jt * 16 + m) * DIM + kc * 32 + quad * 8];
                    acc[jt] = __builtin_amdgcn_mfma_f32_16x16x32_bf16(af, bf, acc[jt], 0, 0, 0);
                }
            }
            // epilogue: wave-private LDS region -> coalesced row-major stores
            unsigned short* ob = &obuf[wid * 16 * WSTRIDE];
#pragma unroll
            for (int jt = 0; jt < 8; ++jt)
#pragma unroll
                for (int r = 0; r < 4; ++r)
                    ob[(quad * 4 + r) * WSTRIDE + jt * 16 + m] = f2bf(acc[jt][r]);
#pragma unroll
            for (int it = 0; it < 4; ++it) {
                int idx = it * 64 + lane;
                int r = idx >> 4;
                int cb = idx & 15;
                int grow = row_base - wid * 16 + (wid * 16 + r);  // = row_base + r
                if (grow < N) {
                    short8 v = *(const short8*)&ob[r * WSTRIDE + cb * 8];
                    *(short8*)(xlin + (size_t)grow * DIM + cb * 8) = v;
                }
            }
        }
    }
    __threadfence();
    grid.sync();

    // ================= Phase B: per-bin counting sort (R9-verified) ==========
    {
        int* ldeg = (int*)smem;
        int* sa = ldeg + BINSZ;
        int* sb2 = sa + BINSZ;
        int* lcur = sb2 + BINSZ;
        for (int b = bid; b < NB; b += G) {
            int s0 = b * CAPB;
            int s1 = s0 + binCursor[b];
            if (t < BINSZ) { ldeg[t] = 0; lcur[t] = 0; }
            __syncthreads();
            for (int i = s0 + t; i < s1; i += 512)
                atomicAdd(&ldeg[binned[i] >> 17], 1);
            __syncthreads();
            if (t < BINSZ) sa[t] = ldeg[t];
            __syncthreads();
            int* src = sa; int* dstp = sb2;
            for (int step = 1; step < BINSZ; step <<= 1) {
                if (t < BINSZ) {
                    int v = src[t];
                    if (t >= step) v += src[t - step];
                    dstp[t] = v;
                }
                __syncthreads();
                int* tmp = src; src = dstp; dstp = tmp;
            }
            if (t < BINSZ) {
                int d = ldeg[t];
                int startoff = src[t] - d;           // exclusive
                int n = (b << BINSHIFT) + t;
                if (n < N) {
                    rowinfo[n] = make_int2(s0 + startoff, d);
                    dinv[n] = rsqrtf((float)(d + 1));   // +1 self loop
                }
                dstp[t] = startoff;
            }
            __syncthreads();
            for (int i = s0 + t; i < s1; i += 512) {
                unsigned p = binned[i];
                int li = p >> 17;
                col[s0 + dstp[li] + atomicAdd(&lcur[li], 1)] = (int)(p & 0x1FFFFu);
            }
            __syncthreads();   // protect ldeg reuse on next grid-stride bin
        }
    }
    __threadfence();
    grid.sync();

    // ================= Phase C: aggregate (R6-verified 66us structure) =======
    {
        int lane = t & 15;               // owns dims 8*lane .. 8*lane+7
        const uint4* xl = (const uint4*)xlin;
        int NGRP = (N + 31) >> 5;        // 32 nodes per block-pass
        for (int grp = bid; grp < NGRP; grp += G) {
            int node = grp * 32 + (t >> 4);
            if (node >= N) continue;
            float di = dinv[node];
            int2 ri = rowinfo[node];
            int r0 = ri.x, r1 = ri.x + ri.y;

            float acc[8] = {};
            bf8_axpy(xl[(size_t)node * 16 + lane], di, acc);   // self loop

            for (int i = r0; i < r1; i += 4) {
                int rem = r1 - i;
                int s0 = col[i];
                int s1 = col[rem > 1 ? i + 1 : i];
                int s2 = col[rem > 2 ? i + 2 : i];
                int s3 = col[rem > 3 ? i + 3 : i];
                float d0 = dinv[s0];
                float d1 = rem > 1 ? dinv[s1] : 0.f;
                float d2 = rem > 2 ? dinv[s2] : 0.f;
                float d3 = rem > 3 ? dinv[s3] : 0.f;
                uint4 v0 = xl[(size_t)s0 * 16 + lane];
                uint4 v1 = xl[(size_t)s1 * 16 + lane];
                uint4 v2 = xl[(size_t)s2 * 16 + lane];
                uint4 v3 = xl[(size_t)s3 * 16 + lane];
                bf8_axpy(v0, d0, acc);
                bf8_axpy(v1, d1, acc);
                bf8_axpy(v2, d2, acc);
                bf8_axpy(v3, d3, acc);
            }

            const float4* b4 = (const float4*)(bias + lane * 8);
            float4 bl = b4[0], bh = b4[1];
            float4 olo = make_float4(di * acc[0] + bl.x, di * acc[1] + bl.y,
                                     di * acc[2] + bl.z, di * acc[3] + bl.w);
            float4 ohi = make_float4(di * acc[4] + bh.x, di * acc[5] + bh.y,
                                     di * acc[6] + bh.z, di * acc[7] + bh.w);
            float4* op = (float4*)(out + (size_t)node * DIM + lane * 8);
            op[0] = olo;
            op[1] = ohi;
        }
    }
}

// ---- launch ----------------------------------------------------------------

extern "C" void kernel_launch(void* const* d_in, const int* in_sizes, int n_in,
                              void* d_out, int out_size, void* d_ws, size_t ws_size,
                              hipStream_t stream) {
    const float* x    = (const float*)d_in[0];
    const int*   ei   = (const int*)d_in[1];
    const float* W    = (const float*)d_in[2];
    const float* bias = (const float*)d_in[3];
    float* out = (float*)d_out;

    int N = in_sizes[0] / DIM;      // 100000
    int E = in_sizes[1] / 2;        // 1600000

    char* ws = (char*)d_ws;
    size_t off = 0;
    auto alloc = [&](size_t bytes) { size_t o = off; off = (off + bytes + 255) & ~(size_t)255; return o; };
    unsigned short* xlin = (unsigned short*)(ws + alloc((size_t)N * DIM * 2));   // 25.6 MB
    unsigned* binned = (unsigned*)(ws + alloc((size_t)NB * CAPB * 4));           // 12.8 MB
    int*  col      = (int*)  (ws + alloc((size_t)NB * CAPB * 4));                // 12.8 MB
    int2* rowinfo  = (int2*) (ws + alloc((size_t)N * 8));
    float* dinv    = (float*)(ws + alloc((size_t)N * 4));
    int*  binCursor= (int*)  (ws + alloc((size_t)NB * 4 + 256));
    unsigned short* wbf = (unsigned short*)(ws + alloc((size_t)DIM * DIM * 2));  // 32 KB

    // co-resident grid for cooperative launch (target 3 blocks/CU * 256 CU)
    int maxb = 0;
    hipOccupancyMaxActiveBlocksPerMultiprocessor(&maxb, gcn_mega, 512, 0);
    if (maxb < 1) maxb = 1;
    int G = maxb * 256;
    if (G > 768) G = 768;
    if (G & 1) --G;
    if (G < 2) G = 2;
    int SB = G / 2;

    hipMemsetAsync(binCursor, 0, (size_t)NB * 4, stream);
    wconv<<<4, 256, 0, stream>>>(W, wbf);

    void* args[] = { (void*)&ei, (void*)&E, (void*)&binCursor, (void*)&binned,
                     (void*)&col, (void*)&rowinfo, (void*)&dinv, (void*)&x,
                     (void*)&wbf, (void*)&xlin, (void*)&bias, (void*)&out,
                     (void*)&N, (void*)&SB };
    hipLaunchCooperativeKernel(gcn_mega, dim3(G), dim3(512), args, 0, stream);
}

// Round 8
// 365.951 us; speedup vs baseline: 1.5240x; 1.5240x over previous
//
#include <hip/hip_runtime.h>

// GCNConv forward: out = D^-1/2 (A+I) D^-1/2 (x W^T) + b
// N=100000, E=1600000, DIM=128. fp32 in/out, edge_index as int32.
//
// R13: R12's cooperative mega-kernel falsified (714us: phase barriers + grid
// cap + coherence flushes). Back to discrete dispatches but only THREE:
//   K0 init: zero cursors + W->bf16 (replaces memset+wconv, saves a boundary)
//   K1 fused_pre: scatter (0..511) || gemm (512..1293) || sort (1294..1684)
//       - scatter/gemm overlap proven by R8 (combined dispatch < 66us)
//       - sort blocks spin on a device-scope done counter (release: threadfence
//         + atomic add by each scatter block; acquire: atomic load). No
//         deadlock: resident capacity ~768 blocks > 391 waiters.
//   K2 aggregate: the twice-verified 66us kernel, byte-identical.

#define DIM 128
#define BINSHIFT 8
#define BINSZ 256            // nodes per bin
#define NB 391               // ceil(100000/256)
#define CAPB 8192            // edges per bin capacity (mean 4096, sd ~64)
#define BUFCAP 32            // LDS slots per bin per scatter block (mean 8)
#define SBLK 512             // scatter blocks
#define WSTRIDE 136          // shorts per LDS row in gemm epilogue buffer
#define SMEMSZ 51616         // scatter role: cnt(1568B) + sbuf(391*32*4B)

typedef __attribute__((ext_vector_type(8))) short short8;
typedef __attribute__((ext_vector_type(4))) float f32x4;
typedef __attribute__((ext_vector_type(4))) unsigned short ushort4v;

__device__ inline unsigned short f2bf(float f) {
    unsigned u = __builtin_bit_cast(unsigned, f);
    return (unsigned short)((u + 0x7FFFu + ((u >> 16) & 1u)) >> 16);
}
__device__ inline float bflo(unsigned u) { return __builtin_bit_cast(float, u << 16); }
__device__ inline float bfhi(unsigned u) { return __builtin_bit_cast(float, u & 0xFFFF0000u); }

__device__ inline void bf8_axpy(uint4 v, float s, float* acc) {
    acc[0] = fmaf(s, bflo(v.x), acc[0]);
    acc[1] = fmaf(s, bfhi(v.x), acc[1]);
    acc[2] = fmaf(s, bflo(v.y), acc[2]);
    acc[3] = fmaf(s, bfhi(v.y), acc[3]);
    acc[4] = fmaf(s, bflo(v.z), acc[4]);
    acc[5] = fmaf(s, bfhi(v.z), acc[5]);
    acc[6] = fmaf(s, bflo(v.w), acc[6]);
    acc[7] = fmaf(s, bfhi(v.w), acc[7]);
}

// ---- K0: init -- blocks 0..3 convert W, block 4 zeros cursors + done flag --
__global__ __launch_bounds__(256) void init_k(const float* __restrict__ W,
                                              unsigned short* __restrict__ wbf,
                                              int* __restrict__ binCursor) {
    int t = threadIdx.x;
    if (blockIdx.x < 4) {
        int base = blockIdx.x * 1024 + t * 4;
#pragma unroll
        for (int i = 0; i < 4; ++i) {
            float4 w4 = ((const float4*)W)[base + i];
            ushort4v o; o.x = f2bf(w4.x); o.y = f2bf(w4.y); o.z = f2bf(w4.z); o.w = f2bf(w4.w);
            ((ushort4v*)wbf)[base + i] = o;
        }
    } else {
        for (int i = t; i <= NB; i += 256) binCursor[i] = 0;   // incl. done flag
    }
}

// ---- K1: scatter || gemm || (spin)sort -------------------------------------
__global__ __launch_bounds__(512) void fused_pre(
        const int* __restrict__ ei, int E,
        int* __restrict__ binCursor, unsigned* __restrict__ binned,
        int* __restrict__ col, int2* __restrict__ rowinfo, float* __restrict__ dinv,
        const float* __restrict__ x, const unsigned short* __restrict__ wbf,
        unsigned short* __restrict__ xlin, int N, int GB) {
    __shared__ __align__(16) char smem[SMEMSZ];
    int t = threadIdx.x;
    int bid = blockIdx.x;
    int* done = binCursor + NB;

    if (bid < SBLK) {
        // ---- scatter role (R10/R11-verified bucket design)
        int* cnt = (int*)smem;
        unsigned* sbuf = (unsigned*)(smem + 1568);
        for (int i = t; i < NB; i += 512) cnt[i] = 0;
        __syncthreads();
        int chunk = (E + SBLK - 1) / SBLK;
        int base = bid * chunk, end = min(E, base + chunk);
        for (int i = base + t; i < end; i += 512) {
            int s = ei[i];
            int d = ei[E + i];
            int b = d >> BINSHIFT;
            unsigned p = ((unsigned)(d & (BINSZ - 1)) << 17) | (unsigned)s;
            int pos = atomicAdd(&cnt[b], 1);
            if (pos < BUFCAP) sbuf[b * BUFCAP + pos] = p;
            else binned[(size_t)b * CAPB + atomicAdd(&binCursor[b], 1)] = p;  // rare
        }
        __syncthreads();
        for (int b = t; b < NB; b += 512) {
            int c = min(cnt[b], BUFCAP);
            if (c > 0) {
                int gb = atomicAdd(&binCursor[b], c);
                unsigned* gp = binned + (size_t)b * CAPB + gb;
                const unsigned* lp = &sbuf[b * BUFCAP];
                for (int j = 0; j < c; ++j) gp[j] = lp[j];
            }
        }
        // release: my stores drained at the barrier; flush L2, signal done.
        __threadfence();
        __syncthreads();
        if (t == 0)
            __hip_atomic_fetch_add(done, 1, __ATOMIC_RELEASE, __HIP_MEMORY_SCOPE_AGENT);
        return;
    }

    if (bid < SBLK + GB) {
        // ---- gemm role (R9-verified): 8 waves x 16 rows = 128 rows per block
        unsigned short* obuf = (unsigned short*)smem;
        int wid = t >> 6, lane = t & 63;
        int m = lane & 15, quad = lane >> 4;
        int row_base = (bid - SBLK) * 128 + wid * 16;

        f32x4 acc[8];
#pragma unroll
        for (int j = 0; j < 8; ++j) acc[j] = (f32x4){0.f, 0.f, 0.f, 0.f};

        int arow = row_base + m;
        if (arow >= N) arow = N - 1;
        const float* xr = x + (size_t)arow * DIM + quad * 8;

#pragma unroll
        for (int kc = 0; kc < 4; ++kc) {
            float4 a0 = *(const float4*)(xr + kc * 32);
            float4 a1 = *(const float4*)(xr + kc * 32 + 4);
            short8 af;
            af[0] = (short)f2bf(a0.x); af[1] = (short)f2bf(a0.y);
            af[2] = (short)f2bf(a0.z); af[3] = (short)f2bf(a0.w);
            af[4] = (short)f2bf(a1.x); af[5] = (short)f2bf(a1.y);
            af[6] = (short)f2bf(a1.z); af[7] = (short)f2bf(a1.w);
#pragma unroll
            for (int jt = 0; jt < 8; ++jt) {
                short8 bf = *(const short8*)&wbf[(jt * 16 + m) * DIM + kc * 32 + quad * 8];
                acc[jt] = __builtin_amdgcn_mfma_f32_16x16x32_bf16(af, bf, acc[jt], 0, 0, 0);
            }
        }

        unsigned short* ob = &obuf[wid * 16 * WSTRIDE];
#pragma unroll
        for (int jt = 0; jt < 8; ++jt)
#pragma unroll
            for (int r = 0; r < 4; ++r)
                ob[(quad * 4 + r) * WSTRIDE + jt * 16 + m] = f2bf(acc[jt][r]);
        __syncthreads();
#pragma unroll
        for (int it = 0; it < 4; ++it) {
            int idx = it * 64 + lane;
            int r = idx >> 4;
            int cb = idx & 15;
            int grow = row_base + r;
            if (grow < N) {
                short8 v = *(const short8*)&ob[r * WSTRIDE + cb * 8];
                *(short8*)(xlin + (size_t)grow * DIM + cb * 8) = v;
            }
        }
        return;
    }

    // ---- sort role (R9-verified counting sort), gated on scatter completion
    {
        int b = bid - SBLK - GB;          // 0..NB-1
        if (t == 0) {
            while (__hip_atomic_load(done, __ATOMIC_ACQUIRE, __HIP_MEMORY_SCOPE_AGENT) < SBLK)
                __builtin_amdgcn_s_sleep(8);
        }
        __syncthreads();

        int* ldeg = (int*)smem;
        int* sa   = ldeg + BINSZ;
        int* sb2  = sa + BINSZ;
        int* lcur = sb2 + BINSZ;
        int s0 = b * CAPB;
        int s1 = s0 + binCursor[b];

        if (t < BINSZ) { ldeg[t] = 0; lcur[t] = 0; }
        __syncthreads();
        for (int i = s0 + t; i < s1; i += 512)
            atomicAdd(&ldeg[binned[i] >> 17], 1);
        __syncthreads();
        if (t < BINSZ) sa[t] = ldeg[t];
        __syncthreads();
        int* src = sa; int* dstp = sb2;
        for (int step = 1; step < BINSZ; step <<= 1) {
            if (t < BINSZ) {
                int v = src[t];
                if (t >= step) v += src[t - step];
                dstp[t] = v;
            }
            __syncthreads();
            int* tmp = src; src = dstp; dstp = tmp;
        }
        if (t < BINSZ) {
            int d = ldeg[t];
            int startoff = src[t] - d;           // exclusive
            int n = (b << BINSHIFT) + t;
            if (n < N) {
                rowinfo[n] = make_int2(s0 + startoff, d);
                dinv[n] = rsqrtf((float)(d + 1));   // +1 self loop
            }
            dstp[t] = startoff;
        }
        __syncthreads();
        for (int i = s0 + t; i < s1; i += 512) {
            unsigned p = binned[i];
            int li = p >> 17;
            col[s0 + dstp[li] + atomicAdd(&lcur[li], 1)] = (int)(p & 0x1FFFFu);
        }
    }
}

// ---- K2: aggregate (verified 66us structure, byte-identical) ---------------
__global__ __launch_bounds__(256) void aggregate(const unsigned short* __restrict__ xlin,
                                                 const int* __restrict__ col,
                                                 const int2* __restrict__ rowinfo,
                                                 const float* __restrict__ dinv,
                                                 const float* __restrict__ bias,
                                                 float* __restrict__ out, int N) {
    int node = blockIdx.x * 16 + (threadIdx.x >> 4);
    int lane = threadIdx.x & 15;          // owns dims 8*lane .. 8*lane+7
    if (node >= N) return;

    float di = dinv[node];
    int2 ri = rowinfo[node];
    int r0 = ri.x, r1 = ri.x + ri.y;

    const uint4* xl = (const uint4*)xlin;     // 8 bf16 per uint4; 16 per row
    float acc[8] = {};
    bf8_axpy(xl[(size_t)node * 16 + lane], di, acc);   // self loop

    for (int i = r0; i < r1; i += 4) {
        int rem = r1 - i;
        int s0 = col[i];
        int s1 = col[rem > 1 ? i + 1 : i];
        int s2 = col[rem > 2 ? i + 2 : i];
        int s3 = col[rem > 3 ? i + 3 : i];
        float d0 = dinv[s0];
        float d1 = rem > 1 ? dinv[s1] : 0.f;
        float d2 = rem > 2 ? dinv[s2] : 0.f;
        float d3 = rem > 3 ? dinv[s3] : 0.f;
        uint4 v0 = xl[(size_t)s0 * 16 + lane];
        uint4 v1 = xl[(size_t)s1 * 16 + lane];
        uint4 v2 = xl[(size_t)s2 * 16 + lane];
        uint4 v3 = xl[(size_t)s3 * 16 + lane];
        bf8_axpy(v0, d0, acc);
        bf8_axpy(v1, d1, acc);
        bf8_axpy(v2, d2, acc);
        bf8_axpy(v3, d3, acc);
    }

    const float4* b4 = (const float4*)(bias + lane * 8);
    float4 bl = b4[0], bh = b4[1];
    float4 olo = make_float4(di * acc[0] + bl.x, di * acc[1] + bl.y,
                             di * acc[2] + bl.z, di * acc[3] + bl.w);
    float4 ohi = make_float4(di * acc[4] + bh.x, di * acc[5] + bh.y,
                             di * acc[6] + bh.z, di * acc[7] + bh.w);
    float4* op = (float4*)(out + (size_t)node * DIM + lane * 8);
    op[0] = olo;
    op[1] = ohi;
}

// ---- launch ----------------------------------------------------------------

extern "C" void kernel_launch(void* const* d_in, const int* in_sizes, int n_in,
                              void* d_out, int out_size, void* d_ws, size_t ws_size,
                              hipStream_t stream) {
    const float* x    = (const float*)d_in[0];
    const int*   ei   = (const int*)d_in[1];
    const float* W    = (const float*)d_in[2];
    const float* bias = (const float*)d_in[3];
    float* out = (float*)d_out;

    int N = in_sizes[0] / DIM;      // 100000
    int E = in_sizes[1] / 2;        // 1600000

    char* ws = (char*)d_ws;
    size_t off = 0;
    auto alloc = [&](size_t bytes) { size_t o = off; off = (off + bytes + 255) & ~(size_t)255; return o; };
    unsigned short* xlin = (unsigned short*)(ws + alloc((size_t)N * DIM * 2));   // 25.6 MB
    unsigned* binned = (unsigned*)(ws + alloc((size_t)NB * CAPB * 4));           // 12.8 MB
    int*  col      = (int*)  (ws + alloc((size_t)NB * CAPB * 4));                // 12.8 MB
    int2* rowinfo  = (int2*) (ws + alloc((size_t)N * 8));
    float* dinv    = (float*)(ws + alloc((size_t)N * 4));
    int*  binCursor= (int*)  (ws + alloc((size_t)(NB + 1) * 4));                 // +done flag
    unsigned short* wbf = (unsigned short*)(ws + alloc((size_t)DIM * DIM * 2));  // 32 KB

    int GB = (N + 127) / 128;             // gemm blocks (782)

    init_k<<<5, 256, 0, stream>>>(W, wbf, binCursor);
    fused_pre<<<SBLK + GB + NB, 512, 0, stream>>>(ei, E, binCursor, binned,
                                                  col, rowinfo, dinv, x, wbf, xlin, N, GB);
    aggregate<<<(N + 15) / 16, 256, 0, stream>>>(xlin, col, rowinfo, dinv, bias, out, N);
}

// Round 9
// 227.785 us; speedup vs baseline: 2.4483x; 1.6066x over previous
//
#include <hip/hip_runtime.h>
#include <hip/hip_bf16.h>

// GCNConv forward: out = D^-1/2 (A+I) D^-1/2 (x W^T) + b
// N=100000, E=1600000, DIM=128. fp32 in/out, edge_index as int32.
//
// R14: R12/R13 proved intra-dispatch cross-block sync is a loser on gfx950
// (device-scope fences defeat L2). Revert to the R6-exact 4-dispatch pipeline
// (best measured: 227.6us) with ONE change: the scatter kernel gets 512 blocks
// (was 256) and 4-edge ILP batching (int4 loads, 4 independent LDS-atomic->
// store chains per thread) to attack its latency-bound inner loop.
//   memset(cursors) -> scatter+wconv -> [csr || gemm] -> aggregate

#define DIM 128
#define BINSHIFT 9
#define BINSZ 512            // nodes per bin
#define NB 196               // ceil(100000/512)
#define MAXNB 256
#define CAPB 16384           // edges per bin capacity (mean 8192, sd ~90)
#define WSTRIDE 136          // shorts per LDS row in gemm epilogue buffer
#define SCAT 512             // scatter blocks

typedef __attribute__((ext_vector_type(8))) short short8;
typedef __attribute__((ext_vector_type(4))) float f32x4;
typedef __attribute__((ext_vector_type(4))) unsigned short ushort4v;

__device__ inline unsigned short f2bf(float f) {
    unsigned u = __builtin_bit_cast(unsigned, f);
    return (unsigned short)((u + 0x7FFFu + ((u >> 16) & 1u)) >> 16);
}
__device__ inline float bflo(unsigned u) { return __builtin_bit_cast(float, u << 16); }
__device__ inline float bfhi(unsigned u) { return __builtin_bit_cast(float, u & 0xFFFF0000u); }

__device__ inline void bf8_axpy(uint4 v, float s, float* acc) {
    acc[0] = fmaf(s, bflo(v.x), acc[0]);
    acc[1] = fmaf(s, bfhi(v.x), acc[1]);
    acc[2] = fmaf(s, bflo(v.y), acc[2]);
    acc[3] = fmaf(s, bfhi(v.y), acc[3]);
    acc[4] = fmaf(s, bflo(v.z), acc[4]);
    acc[5] = fmaf(s, bfhi(v.z), acc[5]);
    acc[6] = fmaf(s, bflo(v.w), acc[6]);
    acc[7] = fmaf(s, bfhi(v.w), acc[7]);
}

// ---- K1: binned scatter (blocks 0..511, 4-edge ILP) + W->bf16 (512..515) ---
__global__ __launch_bounds__(256) void scatter_wconv(const int* __restrict__ ei, int E,
                                                     int* __restrict__ binCursor,
                                                     int2* __restrict__ binned,
                                                     const float* __restrict__ W,
                                                     unsigned short* __restrict__ wbf) {
    int t = threadIdx.x;
    if (blockIdx.x >= SCAT) {
        int base = (blockIdx.x - SCAT) * 1024 + t * 4;  // ushort4v chunks
#pragma unroll
        for (int i = 0; i < 4; ++i) {
            float4 w4 = ((const float4*)W)[base + i];
            ushort4v o; o.x = f2bf(w4.x); o.y = f2bf(w4.y); o.z = f2bf(w4.z); o.w = f2bf(w4.w);
            ((ushort4v*)wbf)[base + i] = o;
        }
        return;
    }
    __shared__ int lh[MAXNB];
    __shared__ int lbase[MAXNB];
    lh[t] = 0;
    __syncthreads();

    int EQ = E >> 2;                       // int4 quads (E=1.6M divisible by 4)
    int nq = (EQ + SCAT - 1) / SCAT;       // quads per block
    int q0 = blockIdx.x * nq, q1 = min(EQ, q0 + nq);
    const int4* d4p = (const int4*)(ei + E);
    const int4* s4p = (const int4*)ei;

    // pass 1: histogram (4 independent atomics per iteration)
    for (int q = q0 + t; q < q1; q += 256) {
        int4 d = d4p[q];
        atomicAdd(&lh[d.x >> BINSHIFT], 1);
        atomicAdd(&lh[d.y >> BINSHIFT], 1);
        atomicAdd(&lh[d.z >> BINSHIFT], 1);
        atomicAdd(&lh[d.w >> BINSHIFT], 1);
    }
    if (blockIdx.x == 0)    // tail edges (robustness; none when E%4==0)
        for (int i = (EQ << 2) + t; i < E; i += 256)
            atomicAdd(&lh[ei[E + i] >> BINSHIFT], 1);
    __syncthreads();
    if (t < NB) {
        int c = lh[t];
        lbase[t] = c ? atomicAdd(&binCursor[t], c) : 0;
        lh[t] = 0;
    }
    __syncthreads();
    // pass 2: placement (4 independent atomic->store chains per iteration)
    for (int q = q0 + t; q < q1; q += 256) {
        int4 s = s4p[q];
        int4 d = d4p[q];
        int b0 = d.x >> BINSHIFT, b1 = d.y >> BINSHIFT;
        int b2 = d.z >> BINSHIFT, b3 = d.w >> BINSHIFT;
        int p0 = b0 * CAPB + lbase[b0] + atomicAdd(&lh[b0], 1);
        int p1 = b1 * CAPB + lbase[b1] + atomicAdd(&lh[b1], 1);
        int p2 = b2 * CAPB + lbase[b2] + atomicAdd(&lh[b2], 1);
        int p3 = b3 * CAPB + lbase[b3] + atomicAdd(&lh[b3], 1);
        binned[p0] = make_int2(s.x, d.x);
        binned[p1] = make_int2(s.y, d.y);
        binned[p2] = make_int2(s.z, d.z);
        binned[p3] = make_int2(s.w, d.w);
    }
    if (blockIdx.x == 0)
        for (int i = (EQ << 2) + t; i < E; i += 256) {
            int s = ei[i], d = ei[E + i];
            int b = d >> BINSHIFT;
            binned[b * CAPB + lbase[b] + atomicAdd(&lh[b], 1)] = make_int2(s, d);
        }
}

// ---- K2: csr_build (blocks 0..NB-1) || MFMA gemm (blocks NB..) -------------
// (byte-identical to the 227.6us R6 baseline)
__global__ __launch_bounds__(256) void csr_gemm(const int2* __restrict__ binned,
                                                const int* __restrict__ binCursor,
                                                int* __restrict__ col,
                                                int2* __restrict__ rowinfo,
                                                float* __restrict__ dinv,
                                                const float* __restrict__ x,
                                                const unsigned short* __restrict__ wbf,
                                                unsigned short* __restrict__ xlin, int N) {
    __shared__ unsigned short obuf[4 * 16 * WSTRIDE];   // gemm epilogue (17.4 KB)
    __shared__ int ldeg[BINSZ], sa[BINSZ], sb[BINSZ], lcur[BINSZ];  // csr (8 KB)
    int t = threadIdx.x;

    if (blockIdx.x < NB) {
        int b = blockIdx.x;
        int s0 = b * CAPB;
        int s1 = s0 + binCursor[b];
        for (int i = t; i < BINSZ; i += 256) { ldeg[i] = 0; lcur[i] = 0; }
        __syncthreads();
        for (int i = s0 + t; i < s1; i += 256)
            atomicAdd(&ldeg[binned[i].y & (BINSZ - 1)], 1);
        __syncthreads();
        for (int i = t; i < BINSZ; i += 256) sa[i] = ldeg[i];
        __syncthreads();
        int* src = sa; int* dstp = sb;
        for (int step = 1; step < BINSZ; step <<= 1) {
            for (int i = t; i < BINSZ; i += 256) {
                int v = src[i];
                if (i >= step) v += src[i - step];
                dstp[i] = v;
            }
            __syncthreads();
            int* tmp = src; src = dstp; dstp = tmp;
        }
        for (int i = t; i < BINSZ; i += 256) dstp[i] = src[i] - ldeg[i];  // exclusive
        __syncthreads();
        for (int i = t; i < BINSZ; i += 256) {
            int n = (b << BINSHIFT) + i;
            if (n < N) {
                rowinfo[n] = make_int2(s0 + dstp[i], ldeg[i]);
                dinv[n] = rsqrtf((float)(ldeg[i] + 1));   // +1 self loop
            }
        }
        for (int i = s0 + t; i < s1; i += 256) {
            int2 e = binned[i];
            int li = e.y & (BINSZ - 1);
            col[s0 + dstp[li] + atomicAdd(&lcur[li], 1)] = e.x;
        }
        return;
    }

    // ---- GEMM role: wave computes 16 rows x 128 cols; B-frags from bf16 W (L1)
    int wid = t >> 6, lane = t & 63;
    int m = lane & 15, quad = lane >> 4;
    int row_base = (blockIdx.x - NB) * 64 + wid * 16;

    f32x4 acc[8];
#pragma unroll
    for (int j = 0; j < 8; ++j) acc[j] = (f32x4){0.f, 0.f, 0.f, 0.f};

    int arow = row_base + m;
    if (arow >= N) arow = N - 1;
    const float* xr = x + (size_t)arow * DIM + quad * 8;

#pragma unroll
    for (int kc = 0; kc < 4; ++kc) {
        float4 a0 = *(const float4*)(xr + kc * 32);
        float4 a1 = *(const float4*)(xr + kc * 32 + 4);
        short8 af;
        af[0] = (short)f2bf(a0.x); af[1] = (short)f2bf(a0.y);
        af[2] = (short)f2bf(a0.z); af[3] = (short)f2bf(a0.w);
        af[4] = (short)f2bf(a1.x); af[5] = (short)f2bf(a1.y);
        af[6] = (short)f2bf(a1.z); af[7] = (short)f2bf(a1.w);
#pragma unroll
        for (int jt = 0; jt < 8; ++jt) {
            short8 bf = *(const short8*)&wbf[(jt * 16 + m) * DIM + kc * 32 + quad * 8];
            acc[jt] = __builtin_amdgcn_mfma_f32_16x16x32_bf16(af, bf, acc[jt], 0, 0, 0);
        }
    }

    unsigned short* ob = &obuf[wid * 16 * WSTRIDE];
#pragma unroll
    for (int jt = 0; jt < 8; ++jt)
#pragma unroll
        for (int r = 0; r < 4; ++r)
            ob[(quad * 4 + r) * WSTRIDE + jt * 16 + m] = f2bf(acc[jt][r]);
#pragma unroll
    for (int it = 0; it < 4; ++it) {
        int idx = it * 64 + lane;
        int r = idx >> 4;
        int cb = idx & 15;
        int grow = row_base + r;
        if (grow < N) {
            short8 v = *(const short8*)&ob[r * WSTRIDE + cb * 8];
            *(short8*)(xlin + (size_t)grow * DIM + cb * 8) = v;
        }
    }
}

// ---- K3: aggregate (byte-identical to the verified 66us kernel) ------------
__global__ __launch_bounds__(256) void aggregate(const unsigned short* __restrict__ xlin,
                                                 const int* __restrict__ col,
                                                 const int2* __restrict__ rowinfo,
                                                 const float* __restrict__ dinv,
                                                 const float* __restrict__ bias,
                                                 float* __restrict__ out, int N) {
    int node = blockIdx.x * 16 + (threadIdx.x >> 4);
    int lane = threadIdx.x & 15;          // owns dims 8*lane .. 8*lane+7
    if (node >= N) return;

    float di = dinv[node];
    int2 ri = rowinfo[node];
    int r0 = ri.x, r1 = ri.x + ri.y;

    const uint4* xl = (const uint4*)xlin;     // 8 bf16 per uint4; 16 per row
    float acc[8] = {};
    bf8_axpy(xl[(size_t)node * 16 + lane], di, acc);   // self loop

    for (int i = r0; i < r1; i += 4) {
        int rem = r1 - i;
        int s0 = col[i];
        int s1 = col[rem > 1 ? i + 1 : i];
        int s2 = col[rem > 2 ? i + 2 : i];
        int s3 = col[rem > 3 ? i + 3 : i];
        float d0 = dinv[s0];
        float d1 = rem > 1 ? dinv[s1] : 0.f;
        float d2 = rem > 2 ? dinv[s2] : 0.f;
        float d3 = rem > 3 ? dinv[s3] : 0.f;
        uint4 v0 = xl[(size_t)s0 * 16 + lane];
        uint4 v1 = xl[(size_t)s1 * 16 + lane];
        uint4 v2 = xl[(size_t)s2 * 16 + lane];
        uint4 v3 = xl[(size_t)s3 * 16 + lane];
        bf8_axpy(v0, d0, acc);
        bf8_axpy(v1, d1, acc);
        bf8_axpy(v2, d2, acc);
        bf8_axpy(v3, d3, acc);
    }

    const float4* b4 = (const float4*)(bias + lane * 8);
    float4 bl = b4[0], bh = b4[1];
    float4 olo = make_float4(di * acc[0] + bl.x, di * acc[1] + bl.y,
                             di * acc[2] + bl.z, di * acc[3] + bl.w);
    float4 ohi = make_float4(di * acc[4] + bh.x, di * acc[5] + bh.y,
                             di * acc[6] + bh.z, di * acc[7] + bh.w);
    float4* op = (float4*)(out + (size_t)node * DIM + lane * 8);
    op[0] = olo;
    op[1] = ohi;
}

// ---- launch ----------------------------------------------------------------

extern "C" void kernel_launch(void* const* d_in, const int* in_sizes, int n_in,
                              void* d_out, int out_size, void* d_ws, size_t ws_size,
                              hipStream_t stream) {
    const float* x    = (const float*)d_in[0];
    const int*   ei   = (const int*)d_in[1];
    const float* W    = (const float*)d_in[2];
    const float* bias = (const float*)d_in[3];
    float* out = (float*)d_out;

    const int N = in_sizes[0] / DIM;      // 100000
    const int E = in_sizes[1] / 2;        // 1600000

    char* ws = (char*)d_ws;
    size_t off = 0;
    auto alloc = [&](size_t bytes) { size_t o = off; off = (off + bytes + 255) & ~(size_t)255; return o; };
    unsigned short* xlin = (unsigned short*)(ws + alloc((size_t)N * DIM * 2));   // 25.6 MB
    int2* binned   = (int2*) (ws + alloc((size_t)NB * CAPB * 8));                // 25.7 MB
    int*  col      = (int*)  (ws + alloc((size_t)NB * CAPB * 4 + 256));          // 12.85 MB
    int2* rowinfo  = (int2*) (ws + alloc((size_t)N * 8));
    float* dinv    = (float*)(ws + alloc((size_t)N * 4));
    int*  binCursor= (int*)  (ws + alloc(MAXNB * 4));
    unsigned short* wbf = (unsigned short*)(ws + alloc((size_t)DIM * DIM * 2));  // 32 KB

    hipMemsetAsync(binCursor, 0, MAXNB * 4, stream);
    scatter_wconv<<<SCAT + 4, 256, 0, stream>>>(ei, E, binCursor, binned, W, wbf);
    csr_gemm<<<NB + (N + 63) / 64, 256, 0, stream>>>(
        binned, binCursor, col, rowinfo, dinv, x, wbf, xlin, N);
    aggregate<<<(N + 15) / 16, 256, 0, stream>>>(xlin, col, rowinfo, dinv, bias, out, N);
}